// Round 10
// baseline (86.988 us; speedup 1.0000x reference)
//
#include <hip/hip_runtime.h>
#include <math.h>

#define BATCH   16
#define CH      512           // sequence length L == channels
#define HW      4096          // 64*64
#define NCHUNK  64
#define ROWS    (HW / NCHUNK) // 64 rows per chunk
#define DSTATE  16
#define SCHUNK  16            // scan chunks per sequence
#define CLEN    (CH / SCHUNK) // 32 steps per chunk
#define APPU    8             // f4 per thread in apply_att (best: round 5)

typedef float f4 __attribute__((ext_vector_type(4)));

__device__ __forceinline__ float siluf(float x) {
    return x / (1.0f + expf(-x));
}
__device__ __forceinline__ float softplusf(float x) {
    return (x > 20.0f) ? x : log1pf(expf(x));
}

// ---------------- K1: GAP partial sums, float4 nontemporal ------------------
__global__ void __launch_bounds__(512) gap_partial(const f4* __restrict__ x1,
                                                   f4* __restrict__ partial) {
    int b     = blockIdx.x / NCHUNK;
    int chunk = blockIdx.x % NCHUNK;
    int t  = threadIdx.x;
    int c4 = t & 127;       // float4 column (128 per row of 512 ch)
    int rg = t >> 7;        // 4 row groups
    const f4* p = x1 + ((size_t)b * HW + (size_t)chunk * ROWS) * 128 + c4;
    f4 acc = (f4)(0.f);
    #pragma unroll
    for (int r = rg; r < ROWS; r += 4)
        acc += __builtin_nontemporal_load(p + (size_t)r * 128);
    __shared__ f4 red[4][128];
    red[rg][c4] = acc;
    __syncthreads();
    if (rg == 0) {
        f4 s = red[0][c4] + red[1][c4] + red[2][c4] + red[3][c4];
        partial[(size_t)(chunk * BATCH + b) * 128 + c4] = s;
    }
}

// ---------------- K2: fused finalize + precompute + parallel scan -----------
// One block per batch, 512 threads. Finalize is f4-vectorized with a 2-level
// reduction (16 wide loads/thread instead of 64 scalar) — the finalize was
// the latency-bound bulk of this kernel at only 16 resident blocks.
__global__ void __launch_bounds__(512) mamba_fused(const f4* __restrict__ partial4,
                                                   const float* __restrict__ in_proj_w,
                                                   const float* __restrict__ conv_w,
                                                   const float* __restrict__ conv_b,
                                                   const float* __restrict__ x_proj_w,
                                                   const float* __restrict__ dt_proj_w,
                                                   const float* __restrict__ dt_proj_b,
                                                   const float* __restrict__ A_log,
                                                   const float* __restrict__ Dp,
                                                   const float* __restrict__ out_proj_w,
                                                   float* __restrict__ att)
{
    int b   = blockIdx.x;
    int tid = threadIdx.x;

    // --- 1) finalize pooled row: partial4 is [chunk][B][128] f4 ---
    __shared__ float pool[CH];
    {
        int c4 = tid & 127;     // f4 column
        int kg = tid >> 7;      // 4 chunk groups
        f4 acc = (f4)(0.f);
        #pragma unroll
        for (int k = kg; k < NCHUNK; k += 4)
            acc += partial4[(size_t)(k * BATCH + b) * 128 + c4];
        __shared__ f4 redp[4][128];
        redp[kg][c4] = acc;
        __syncthreads();
        if (kg == 0) {
            f4 s = redp[0][c4] + redp[1][c4] + redp[2][c4] + redp[3][c4];
            s *= (1.0f / (float)HW);
            pool[c4 * 4 + 0] = s.x;
            pool[c4 * 4 + 1] = s.y;
            pool[c4 * 4 + 2] = s.z;
            pool[c4 * 4 + 3] = s.w;
        }
    }
    __syncthreads();

    // --- 2) per-position: conv+silu, gate coef, softplus(dt), skip ---
    __shared__ float sx0[CH], sx1[CH], sdt0[CH], sdt1[CH], scf0[CH], scf1[CH], ssk[CH];
    {
        int l = tid;
        float u0  = pool[l];
        float um1 = (l >= 1) ? pool[l - 1] : 0.f;
        float um2 = (l >= 2) ? pool[l - 2] : 0.f;
        float um3 = (l >= 3) ? pool[l - 3] : 0.f;
        float xs[2], cf[2], dtv[2];
        #pragma unroll
        for (int d = 0; d < 2; ++d) {
            float conv = um3 * conv_w[d * 4 + 0] + um2 * conv_w[d * 4 + 1] +
                         um1 * conv_w[d * 4 + 2] + u0  * conv_w[d * 4 + 3];
            float xc = in_proj_w[d] * conv + conv_b[d];
            xs[d] = siluf(xc);
            float z = u0 * in_proj_w[2 + d];
            cf[d] = siluf(z) * out_proj_w[d];
        }
        float dt_raw = xs[0] * x_proj_w[0] + xs[1] * x_proj_w[1];
        #pragma unroll
        for (int d = 0; d < 2; ++d)
            dtv[d] = softplusf(dt_raw * dt_proj_w[d] + dt_proj_b[d]);
        sx0[l] = xs[0]; sx1[l] = xs[1];
        sdt0[l] = dtv[0]; sdt1[l] = dtv[1];
        scf0[l] = cf[0]; scf1[l] = cf[1];
        ssk[l] = xs[0] * Dp[0] * cf[0] + xs[1] * Dp[1] * cf[1];
    }
    __syncthreads();

    // --- 3) chunked parallel scan: 16 chunks x 32 (d,s) lanes ---
    int ds    = tid & 31;
    int chunk = tid >> 5;
    int si    = ds & 15;
    int d     = ds >> 4;
    float Aval = -expf(A_log[d * DSTATE + si]);
    float wB0 = x_proj_w[(1 + si) * 2],  wB1 = x_proj_w[(1 + si) * 2 + 1];
    float wC0 = x_proj_w[(17 + si) * 2], wC1 = x_proj_w[(17 + si) * 2 + 1];
    const float* sdt = d ? sdt1 : sdt0;
    const float* scf = d ? scf1 : scf0;
    const float* sxd = d ? sx1  : sx0;

    float a_[CLEN], b_[CLEN], c_[CLEN];
    int l0 = chunk * CLEN;
    #pragma unroll
    for (int l = 0; l < CLEN; ++l) {
        int L = l0 + l;
        float x0 = sx0[L], x1v = sx1[L];
        float dt = sdt[L];
        float Bs = x0 * wB0 + x1v * wB1;
        float Cs = x0 * wC0 + x1v * wC1;
        a_[l] = expf(dt * Aval);
        b_[l] = dt * Bs * sxd[L];
        c_[l] = Cs * scf[L];
    }

    // phase 1: per-chunk (P, Q)
    float P = 1.f, Q = 0.f;
    #pragma unroll
    for (int l = 0; l < CLEN; ++l) { P *= a_[l]; Q = fmaf(a_[l], Q, b_[l]); }

    // phase 2: exclusive prefix compose across chunks
    __shared__ float sP[SCHUNK][32], sQ[SCHUNK][32];
    sP[chunk][ds] = P; sQ[chunk][ds] = Q;
    __syncthreads();
    float h = 0.f;
    for (int j = 0; j < chunk; ++j) h = fmaf(sP[j][ds], h, sQ[j][ds]);

    // phase 3: exact in-chunk recurrence + 32-lane reduce
    float* patt = att + (size_t)b * CH + l0;
    #pragma unroll
    for (int l = 0; l < CLEN; ++l) {
        h = fmaf(a_[l], h, b_[l]);
        float p = h * c_[l];
        p += __shfl_xor(p, 1, 32);
        p += __shfl_xor(p, 2, 32);
        p += __shfl_xor(p, 4, 32);
        p += __shfl_xor(p, 8, 32);
        p += __shfl_xor(p, 16, 32);
        if (ds == 0) patt[l] = ssk[l0 + l] + p;
    }
}

// ---------------- K3: out = x2 * att broadcast ------------------------------
// Block = 2048 contiguous f4 (batch and channel sub-index block/thread-
// constant): ONE att4 load per thread, then 8 independent NT loads + 8 NT
// stores (round-5 form — best measured).
__global__ void __launch_bounds__(256) apply_att(const f4* __restrict__ x2,
                                                 const f4* __restrict__ att4,
                                                 f4* __restrict__ out)
{
    size_t base = (size_t)blockIdx.x * (256 * APPU) + threadIdx.x;
    f4 a = att4[((base >> 19) << 7) + (base & 127)];
    f4 v[APPU];
    #pragma unroll
    for (int k = 0; k < APPU; ++k)
        v[k] = __builtin_nontemporal_load(x2 + base + k * 256);
    #pragma unroll
    for (int k = 0; k < APPU; ++k)
        __builtin_nontemporal_store(v[k] * a, out + base + k * 256);
}

extern "C" void kernel_launch(void* const* d_in, const int* in_sizes, int n_in,
                              void* d_out, int out_size, void* d_ws, size_t ws_size,
                              hipStream_t stream) {
    const float* x1         = (const float*)d_in[0];
    const float* x2         = (const float*)d_in[1];
    const float* in_proj_w  = (const float*)d_in[2];
    const float* conv_w     = (const float*)d_in[3];
    const float* conv_b     = (const float*)d_in[4];
    const float* x_proj_w   = (const float*)d_in[5];
    const float* dt_proj_w  = (const float*)d_in[6];
    const float* dt_proj_b  = (const float*)d_in[7];
    const float* A_log      = (const float*)d_in[8];
    const float* Dp         = (const float*)d_in[9];
    const float* out_proj_w = (const float*)d_in[10];

    float* ws = (float*)d_ws;
    size_t o = 0;
    float* partial = ws + o; o += (size_t)NCHUNK * BATCH * CH;  // 524288
    float* attv    = ws + o; o += BATCH * CH;                   // 8192
    (void)ws_size; (void)in_sizes; (void)n_in; (void)out_size;

    gap_partial<<<BATCH * NCHUNK, 512, 0, stream>>>((const f4*)x1, (f4*)partial);
    mamba_fused<<<BATCH, 512, 0, stream>>>((const f4*)partial, in_proj_w, conv_w, conv_b,
                                           x_proj_w, dt_proj_w, dt_proj_b,
                                           A_log, Dp, out_proj_w, attv);
    int n4 = (BATCH * HW * CH) / 4;            // 8388608 f4
    int nblk = n4 / (256 * APPU);              // 4096 blocks
    apply_att<<<nblk, 256, 0, stream>>>((const f4*)x2, (const f4*)attv, (f4*)d_out);
}

// Round 11
// 82.060 us; speedup vs baseline: 1.0601x; 1.0601x over previous
//
#include <hip/hip_runtime.h>
#include <math.h>

#define BATCH   16
#define CH      512           // sequence length L == channels
#define HW      4096          // 64*64
#define NCHUNK  64
#define ROWS    (HW / NCHUNK) // 64 rows per chunk
#define DSTATE  16
#define SCHUNK  16            // scan chunks per sequence
#define CLEN    (CH / SCHUNK) // 32 steps per chunk
#define APPU    8             // f4 per thread in apply_att (best: round 5)

typedef float f4 __attribute__((ext_vector_type(4)));

__device__ __forceinline__ float siluf(float x) {
    return x / (1.0f + expf(-x));
}
__device__ __forceinline__ float softplusf(float x) {
    return (x > 20.0f) ? x : log1pf(expf(x));
}

// ---------------- K1: GAP partial sums, float4 nontemporal ------------------
__global__ void __launch_bounds__(512) gap_partial(const f4* __restrict__ x1,
                                                   f4* __restrict__ partial) {
    int b     = blockIdx.x / NCHUNK;
    int chunk = blockIdx.x % NCHUNK;
    int t  = threadIdx.x;
    int c4 = t & 127;       // float4 column (128 per row of 512 ch)
    int rg = t >> 7;        // 4 row groups
    const f4* p = x1 + ((size_t)b * HW + (size_t)chunk * ROWS) * 128 + c4;
    f4 acc = (f4)(0.f);
    #pragma unroll
    for (int r = rg; r < ROWS; r += 4)
        acc += __builtin_nontemporal_load(p + (size_t)r * 128);
    __shared__ f4 red[4][128];
    red[rg][c4] = acc;
    __syncthreads();
    if (rg == 0) {
        f4 s = red[0][c4] + red[1][c4] + red[2][c4] + red[3][c4];
        partial[(size_t)(chunk * BATCH + b) * 128 + c4] = s;
    }
}

// ---------------- K2: fused finalize + precompute + parallel scan -----------
// One block per batch, 512 threads. Everything between the two big streaming
// kernels stays in LDS/registers — no global round-trips, one launch.
// (Exact round-5 form — the f4-finalize (r10) and recompute variants (r6)
// both regressed; scalar 64-load finalize measured best.)
__global__ void __launch_bounds__(512) mamba_fused(const float* __restrict__ partial,
                                                   const float* __restrict__ in_proj_w,
                                                   const float* __restrict__ conv_w,
                                                   const float* __restrict__ conv_b,
                                                   const float* __restrict__ x_proj_w,
                                                   const float* __restrict__ dt_proj_w,
                                                   const float* __restrict__ dt_proj_b,
                                                   const float* __restrict__ A_log,
                                                   const float* __restrict__ Dp,
                                                   const float* __restrict__ out_proj_w,
                                                   float* __restrict__ att)
{
    int b   = blockIdx.x;
    int tid = threadIdx.x;

    // --- 1) finalize pooled row ---
    __shared__ float pool[CH];
    {
        float s = 0.f;
        #pragma unroll 8
        for (int k = 0; k < NCHUNK; ++k)
            s += partial[(size_t)k * (BATCH * CH) + b * CH + tid];
        pool[tid] = s * (1.0f / (float)HW);
    }
    __syncthreads();

    // --- 2) per-position: conv+silu, gate coef, softplus(dt), skip ---
    __shared__ float sx0[CH], sx1[CH], sdt0[CH], sdt1[CH], scf0[CH], scf1[CH], ssk[CH];
    {
        int l = tid;
        float u0  = pool[l];
        float um1 = (l >= 1) ? pool[l - 1] : 0.f;
        float um2 = (l >= 2) ? pool[l - 2] : 0.f;
        float um3 = (l >= 3) ? pool[l - 3] : 0.f;
        float xs[2], cf[2], dtv[2];
        #pragma unroll
        for (int d = 0; d < 2; ++d) {
            float conv = um3 * conv_w[d * 4 + 0] + um2 * conv_w[d * 4 + 1] +
                         um1 * conv_w[d * 4 + 2] + u0  * conv_w[d * 4 + 3];
            float xc = in_proj_w[d] * conv + conv_b[d];
            xs[d] = siluf(xc);
            float z = u0 * in_proj_w[2 + d];
            cf[d] = siluf(z) * out_proj_w[d];
        }
        float dt_raw = xs[0] * x_proj_w[0] + xs[1] * x_proj_w[1];
        #pragma unroll
        for (int d = 0; d < 2; ++d)
            dtv[d] = softplusf(dt_raw * dt_proj_w[d] + dt_proj_b[d]);
        sx0[l] = xs[0]; sx1[l] = xs[1];
        sdt0[l] = dtv[0]; sdt1[l] = dtv[1];
        scf0[l] = cf[0]; scf1[l] = cf[1];
        ssk[l] = xs[0] * Dp[0] * cf[0] + xs[1] * Dp[1] * cf[1];
    }
    __syncthreads();

    // --- 3) chunked parallel scan: 16 chunks x 32 (d,s) lanes ---
    int ds    = tid & 31;
    int chunk = tid >> 5;
    int si    = ds & 15;
    int d     = ds >> 4;
    float Aval = -expf(A_log[d * DSTATE + si]);
    float wB0 = x_proj_w[(1 + si) * 2],  wB1 = x_proj_w[(1 + si) * 2 + 1];
    float wC0 = x_proj_w[(17 + si) * 2], wC1 = x_proj_w[(17 + si) * 2 + 1];
    const float* sdt = d ? sdt1 : sdt0;
    const float* scf = d ? scf1 : scf0;
    const float* sxd = d ? sx1  : sx0;

    float a_[CLEN], b_[CLEN], c_[CLEN];
    int l0 = chunk * CLEN;
    #pragma unroll
    for (int l = 0; l < CLEN; ++l) {
        int L = l0 + l;
        float x0 = sx0[L], x1v = sx1[L];
        float dt = sdt[L];
        float Bs = x0 * wB0 + x1v * wB1;
        float Cs = x0 * wC0 + x1v * wC1;
        a_[l] = expf(dt * Aval);
        b_[l] = dt * Bs * sxd[L];
        c_[l] = Cs * scf[L];
    }

    // phase 1: per-chunk (P, Q)
    float P = 1.f, Q = 0.f;
    #pragma unroll
    for (int l = 0; l < CLEN; ++l) { P *= a_[l]; Q = fmaf(a_[l], Q, b_[l]); }

    // phase 2: exclusive prefix compose across chunks
    __shared__ float sP[SCHUNK][32], sQ[SCHUNK][32];
    sP[chunk][ds] = P; sQ[chunk][ds] = Q;
    __syncthreads();
    float h = 0.f;
    for (int j = 0; j < chunk; ++j) h = fmaf(sP[j][ds], h, sQ[j][ds]);

    // phase 3: exact in-chunk recurrence + 32-lane reduce
    float* patt = att + (size_t)b * CH + l0;
    #pragma unroll
    for (int l = 0; l < CLEN; ++l) {
        h = fmaf(a_[l], h, b_[l]);
        float p = h * c_[l];
        p += __shfl_xor(p, 1, 32);
        p += __shfl_xor(p, 2, 32);
        p += __shfl_xor(p, 4, 32);
        p += __shfl_xor(p, 8, 32);
        p += __shfl_xor(p, 16, 32);
        if (ds == 0) patt[l] = ssk[l0 + l] + p;
    }
}

// ---------------- K3: out = x2 * att broadcast ------------------------------
// Block = 2048 contiguous f4 (batch and channel sub-index block/thread-
// constant): ONE att4 load per thread, 8 independent loads + 8 NT stores.
// x2 loads are PLAIN CACHED (not NT) — isolating the load cache policy:
// the 6.29 TB/s copy ceiling was measured with cached loads, and NT loads
// give up L2 assist without reducing L3 allocation (round-6 counters).
// Stores stay NT: `out` is never read, no-allocate avoids cache pollution.
__global__ void __launch_bounds__(256) apply_att(const f4* __restrict__ x2,
                                                 const f4* __restrict__ att4,
                                                 f4* __restrict__ out)
{
    size_t base = (size_t)blockIdx.x * (256 * APPU) + threadIdx.x;
    f4 a = att4[((base >> 19) << 7) + (base & 127)];
    f4 v[APPU];
    #pragma unroll
    for (int k = 0; k < APPU; ++k)
        v[k] = x2[base + k * 256];
    #pragma unroll
    for (int k = 0; k < APPU; ++k)
        __builtin_nontemporal_store(v[k] * a, out + base + k * 256);
}

extern "C" void kernel_launch(void* const* d_in, const int* in_sizes, int n_in,
                              void* d_out, int out_size, void* d_ws, size_t ws_size,
                              hipStream_t stream) {
    const float* x1         = (const float*)d_in[0];
    const float* x2         = (const float*)d_in[1];
    const float* in_proj_w  = (const float*)d_in[2];
    const float* conv_w     = (const float*)d_in[3];
    const float* conv_b     = (const float*)d_in[4];
    const float* x_proj_w   = (const float*)d_in[5];
    const float* dt_proj_w  = (const float*)d_in[6];
    const float* dt_proj_b  = (const float*)d_in[7];
    const float* A_log      = (const float*)d_in[8];
    const float* Dp         = (const float*)d_in[9];
    const float* out_proj_w = (const float*)d_in[10];

    float* ws = (float*)d_ws;
    size_t o = 0;
    float* partial = ws + o; o += (size_t)NCHUNK * BATCH * CH;  // 524288
    float* attv    = ws + o; o += BATCH * CH;                   // 8192
    (void)ws_size; (void)in_sizes; (void)n_in; (void)out_size;

    gap_partial<<<BATCH * NCHUNK, 512, 0, stream>>>((const f4*)x1, (f4*)partial);
    mamba_fused<<<BATCH, 512, 0, stream>>>(partial, in_proj_w, conv_w, conv_b,
                                           x_proj_w, dt_proj_w, dt_proj_b,
                                           A_log, Dp, out_proj_w, attv);
    int n4 = (BATCH * HW * CH) / 4;            // 8388608 f4
    int nblk = n4 / (256 * APPU);              // 4096 blocks
    apply_att<<<nblk, 256, 0, stream>>>((const f4*)x2, (const f4*)attv, (f4*)d_out);
}